// Round 1
// baseline (163.056 us; speedup 1.0000x reference)
//
#include <hip/hip_runtime.h>

#define NVOX 120000
#define KVOL 27
#define CH 64
#define TOTAL (NVOX * CH)
#define NF4 (TOTAL / 4)
#define EPSV 1e-5f

typedef __attribute__((ext_vector_type(8))) short bf16x8;
typedef __attribute__((ext_vector_type(8))) unsigned short u16x8;
typedef __attribute__((ext_vector_type(4))) float f32x4;

__device__ __forceinline__ unsigned short f2bf(float f) {
    unsigned int u = __builtin_bit_cast(unsigned int, f);
    u += 0x7FFFu + ((u >> 16) & 1u);          // RNE
    return (unsigned short)(u >> 16);
}

// ---- prep: weight shuffle + feats->bf16 + sentinel row + stats zero --------
// weight fp32 [k][c][d] -> bf16 MFMA-fragment order:
//   wtf[((k*8 + grp)*64 + lane)*8 + j], grp=(d>>4)*2+(c>>5),
//   lane=((c&31)>>3)*16+(d&15), j=c&7   (validated rounds 4-8, unchanged)
// feats fp32 [N][64] -> bf16 [N+1][64], row N = zeros (sentinel for idx<0)
#define WBLK 432                 // 27*64*64 / 256
#define FBLK 3750                // 7,680,000 / (256*8)
__global__ void prep(const float* __restrict__ w, const float* __restrict__ feats,
                     unsigned short* __restrict__ wtf, unsigned short* __restrict__ fb,
                     float* __restrict__ stats) {
    const int b = blockIdx.x;
    const int tid = threadIdx.x;
    if (b < WBLK) {
        const int t = b * 256 + tid;           // t = k*4096 + c*64 + d (coalesced read)
        const int d = t & 63, c = (t >> 6) & 63, k = t >> 12;
        const int grp = (d >> 4) * 2 + (c >> 5);
        const int l = ((c & 31) >> 3) * 16 + (d & 15);
        const int j = c & 7;
        wtf[(((size_t)k * 8 + grp) * 64 + l) * 8 + j] = f2bf(w[t]);
        if (b == 0 && tid < 128) stats[tid] = 0.f;
        if (b == 1 && tid < 8) ((u16x8*)fb)[(size_t)NVOX * 8 + tid] = (u16x8)0;
    } else {
        const int t = (b - WBLK) * 256 + tid;  // handles 8 consecutive floats
        const float4* src = (const float4*)feats + (size_t)t * 2;
        const float4 p0 = src[0];
        const float4 p1 = src[1];
        u16x8 v = {f2bf(p0.x), f2bf(p0.y), f2bf(p0.z), f2bf(p0.w),
                   f2bf(p1.x), f2bf(p1.y), f2bf(p1.z), f2bf(p1.w)};
        ((u16x8*)fb)[t] = v;
    }
}

// ---- conv: barrier-free, 32 voxels/wave (2 m-tiles), branchless bf16 gather
// featsB bf16 direct gather via sentinel row (idx<0 -> row N = zeros): the
// load result IS the MFMA A-fragment -> load->use distance = 1 full k-iter.
// 938 blocks * 128 = 120064 (tail waves fully guarded, NVOX%16==0 so tile
// validity is wave-uniform). launch_bounds(256,4): ~15 waves/CU resident.
__launch_bounds__(256, 4)
__global__ void conv_mfma(const unsigned short* __restrict__ FB,
                          const unsigned short* __restrict__ WtF,
                          const int* __restrict__ nbr,
                          float* __restrict__ out,
                          float* __restrict__ stats) {
    __shared__ float lstats[128];
    const int tid = threadIdx.x;
    const int lane = tid & 63;
    const int m = lane & 15;
    const int q = lane >> 4;
    const int v0 = blockIdx.x * 128 + (tid >> 6) * 32;
    const bool tv[2] = { v0 < NVOX, v0 + 16 < NVOX };
    const int r[2] = { v0 + m, v0 + 16 + m };

    f32x4 acc[2][4];
#pragma unroll
    for (int t = 0; t < 2; ++t)
#pragma unroll
        for (int nt = 0; nt < 4; ++nt)
            acc[t][nt] = (f32x4){0.f, 0.f, 0.f, 0.f};
    if (tid < 128) lstats[tid] = 0.f;
    __syncthreads();                            // lstats ready; no more barriers until epilogue

    const bf16x8* fbv = (const bf16x8*)FB;      // 8 x bf16x8 per 128B row

    // prologue: slice-0 gather, slice-1 indices
    bf16x8 a[2][2];
    unsigned long long msk[2];
    int idxn[2];
#pragma unroll
    for (int t = 0; t < 2; ++t) {
        const int i = tv[t] ? nbr[r[t]] : -1;
        msk[t] = __ballot(i >= 0);
        const bf16x8* row = fbv + (size_t)(i < 0 ? NVOX : i) * 8;
        a[t][0] = row[q];
        a[t][1] = row[q + 4];
        idxn[t] = tv[t] ? nbr[NVOX + r[t]] : -1;
    }

    for (int k = 0; k < KVOL; ++k) {
        // weight fragments for slice k (issue early; L2-hot, all blocks share)
        const unsigned short* wk = WtF + (size_t)k * 4096 + lane * 8;
        bf16x8 bfr[8];
#pragma unroll
        for (int h = 0; h < 8; ++h)
            bfr[h] = *(const bf16x8*)(wk + h * 512);

        // branchless gather for slice k+1 (consumed next iteration)
        unsigned long long mn[2];
        bf16x8 an[2][2];
#pragma unroll
        for (int t = 0; t < 2; ++t) {
            mn[t] = __ballot(idxn[t] >= 0);
            const bf16x8* row = fbv + (size_t)(idxn[t] < 0 ? NVOX : idxn[t]) * 8;
            an[t][0] = row[q];
            an[t][1] = row[q + 4];
        }
        // prefetch indices for slice k+2
        int idxf[2] = {-1, -1};
        if (k + 2 < KVOL) {
            const int* nb = nbr + (size_t)(k + 2) * NVOX;
#pragma unroll
            for (int t = 0; t < 2; ++t) idxf[t] = tv[t] ? nb[r[t]] : -1;
        }

        // compute slice k (a[] loaded one iteration ago)
#pragma unroll
        for (int t = 0; t < 2; ++t) {
            if (msk[t]) {
#pragma unroll
                for (int nt = 0; nt < 4; ++nt) {
                    acc[t][nt] = __builtin_amdgcn_mfma_f32_16x16x32_bf16(a[t][0], bfr[nt * 2 + 0], acc[t][nt], 0, 0, 0);
                    acc[t][nt] = __builtin_amdgcn_mfma_f32_16x16x32_bf16(a[t][1], bfr[nt * 2 + 1], acc[t][nt], 0, 0, 0);
                }
            }
        }

        // shift pipeline
#pragma unroll
        for (int t = 0; t < 2; ++t) {
            a[t][0] = an[t][0];
            a[t][1] = an[t][1];
            msk[t] = mn[t];
            idxn[t] = idxf[t];
        }
    }

    // ---- epilogue: stores + block-reduced BN statistics ----
    // D layout: col = m (channel nt*16+m), row = q*4 + rr (voxel within tile)
#pragma unroll
    for (int t = 0; t < 2; ++t) {
        if (tv[t]) {
            float* ob = out + (size_t)(v0 + t * 16 + q * 4) * CH + m;
#pragma unroll
            for (int nt = 0; nt < 4; ++nt)
#pragma unroll
                for (int rr = 0; rr < 4; ++rr)
                    ob[(size_t)rr * CH + nt * 16] = acc[t][nt][rr];
        }
    }

#pragma unroll
    for (int nt = 0; nt < 4; ++nt) {
        float s = 0.f, s2 = 0.f;
#pragma unroll
        for (int t = 0; t < 2; ++t)
#pragma unroll
            for (int rr = 0; rr < 4; ++rr) {
                const float x = acc[t][nt][rr];   // padded tiles stay exactly 0
                s += x;
                s2 = fmaf(x, x, s2);
            }
        s  += __shfl_xor(s, 16);  s  += __shfl_xor(s, 32);
        s2 += __shfl_xor(s2, 16); s2 += __shfl_xor(s2, 32);
        if (lane < 16) {
            atomicAdd(&lstats[nt * 16 + m], s);
            atomicAdd(&lstats[64 + nt * 16 + m], s2);
        }
    }
    __syncthreads();
    if (tid < 128) atomicAdd(&stats[tid], lstats[tid]);
}

// ---- bn_relu: grid-stride with inline finalize -----------------------------
__launch_bounds__(256)
__global__ void bn_relu(float* __restrict__ out, const float* __restrict__ stats,
                        const float* __restrict__ gamma, const float* __restrict__ beta) {
    __shared__ float sb[128];
    const int tid = threadIdx.x;
    if (tid < 64) {
        const float inv_n = 1.0f / (float)NVOX;
        const float mean = stats[tid] * inv_n;
        const float var = stats[64 + tid] * inv_n - mean * mean;
        const float sc = gamma[tid] * rsqrtf(var + EPSV);
        sb[tid] = sc;
        sb[64 + tid] = beta[tid] - mean * sc;
    }
    __syncthreads();
    float4* o4 = (float4*)out;
    for (int e = blockIdx.x * 256 + tid; e < NF4; e += 960 * 256) {
        float4 x = o4[e];
        const int cb = (e & 15) * 4;
        x.x = fmaxf(fmaf(x.x, sb[cb + 0], sb[64 + cb + 0]), 0.f);
        x.y = fmaxf(fmaf(x.y, sb[cb + 1], sb[64 + cb + 1]), 0.f);
        x.z = fmaxf(fmaf(x.z, sb[cb + 2], sb[64 + cb + 2]), 0.f);
        x.w = fmaxf(fmaf(x.w, sb[cb + 3], sb[64 + cb + 3]), 0.f);
        o4[e] = x;
    }
}

extern "C" void kernel_launch(void* const* d_in, const int* in_sizes, int n_in,
                              void* d_out, int out_size, void* d_ws, size_t ws_size,
                              hipStream_t stream) {
    const float* feats  = (const float*)d_in[0];   // [N, 64]
    const float* weight = (const float*)d_in[1];   // [27, 64, 64]
    const float* gamma  = (const float*)d_in[2];   // [64]
    const float* beta   = (const float*)d_in[3];   // [64]
    const int*   nbr    = (const int*)d_in[4];     // [27, N]
    float* out = (float*)d_out;                    // [N, 64]

    // ws layout: [0,512) stats; [512, 512+221184) WtF bf16 frag-order;
    //            [221696, 221696+15360128) featsB bf16 [N+1][64] (sentinel row N)
    float* stats = (float*)d_ws;
    unsigned short* WtF = (unsigned short*)((char*)d_ws + 512);
    unsigned short* FB  = (unsigned short*)((char*)d_ws + 512 + 221184);

    prep<<<WBLK + FBLK, 256, 0, stream>>>(weight, feats, WtF, FB, stats);
    conv_mfma<<<(NVOX + 127) / 128, 256, 0, stream>>>(FB, WtF, nbr, out, stats);
    bn_relu<<<960, 256, 0, stream>>>(out, stats, gamma, beta);
}

// Round 2
// 153.568 us; speedup vs baseline: 1.0618x; 1.0618x over previous
//
#include <hip/hip_runtime.h>

#define NVOX 120000
#define KVOL 27
#define CH 64
#define TOTAL (NVOX * CH)
#define NF4 (TOTAL / 4)
#define EPSV 1e-5f

typedef __attribute__((ext_vector_type(8))) short bf16x8;
typedef __attribute__((ext_vector_type(8))) unsigned short u16x8;
typedef __attribute__((ext_vector_type(4))) float f32x4;
typedef __attribute__((address_space(1))) const void gconst_t;
typedef __attribute__((address_space(3))) void lvoid_t;

__device__ __forceinline__ unsigned short f2bf(float f) {
    unsigned int u = __builtin_bit_cast(unsigned int, f);
    u += 0x7FFFu + ((u >> 16) & 1u);          // RNE
    return (unsigned short)(u >> 16);
}

// ---- prep: weight shuffle + feats->bf16 + sentinel row + stats zero --------
// weight fp32 [k][c][d] -> bf16 MFMA-fragment order:
//   wtf[((k*8 + grp)*64 + lane)*8 + j], grp=(d>>4)*2+(c>>5),
//   lane=((c&31)>>3)*16+(d&15), j=c&7   (validated rounds 4-8, unchanged)
// feats fp32 [N][64] -> bf16 [N+1][64], row N = zeros (sentinel for idx<0)
#define WBLK 432                 // 27*64*64 / 256
#define FBLK 3750                // 7,680,000 / (256*8)
__global__ void prep(const float* __restrict__ w, const float* __restrict__ feats,
                     unsigned short* __restrict__ wtf, unsigned short* __restrict__ fb,
                     float* __restrict__ stats) {
    const int b = blockIdx.x;
    const int tid = threadIdx.x;
    if (b < WBLK) {
        const int t = b * 256 + tid;           // t = k*4096 + c*64 + d (coalesced read)
        const int d = t & 63, c = (t >> 6) & 63, k = t >> 12;
        const int grp = (d >> 4) * 2 + (c >> 5);
        const int l = ((c & 31) >> 3) * 16 + (d & 15);
        const int j = c & 7;
        wtf[(((size_t)k * 8 + grp) * 64 + l) * 8 + j] = f2bf(w[t]);
        if (b == 0 && tid < 128) stats[tid] = 0.f;
        if (b == 1 && tid < 8) ((u16x8*)fb)[(size_t)NVOX * 8 + tid] = (u16x8)0;
    } else {
        const int t = (b - WBLK) * 256 + tid;  // handles 8 consecutive floats
        const float4* src = (const float4*)feats + (size_t)t * 2;
        const float4 p0 = src[0];
        const float4 p1 = src[1];
        u16x8 v = {f2bf(p0.x), f2bf(p0.y), f2bf(p0.z), f2bf(p0.w),
                   f2bf(p1.x), f2bf(p1.y), f2bf(p1.z), f2bf(p1.w)};
        ((u16x8*)fb)[t] = v;
    }
}

// ---- conv: LDS-staged weights (double-buffered, counted vmcnt), branchless
// sentinel gathers (depth-1), 2 m-tiles/wave, 938 blocks * 128 = 120064.
// Weight slice k (8 KB) staged block-wide via global_load_lds while computing
// slice k-1; raw s_barrier + s_waitcnt vmcnt(6) keeps the 4 gathers + 2 idx
// prefetches in flight across the barrier (T3-minimum / T4 counted-wait).
// Issue order pinned: stage(2) first [sched_barrier], then gathers(4)+idx(2)
// -> vmcnt(6) drains exactly the stage. All loads count-uniform across waves
// (tail block included) so every wave's vmcnt(6) guarantees its staged quarter.
__launch_bounds__(256, 4)
__global__ void conv_mfma(const unsigned short* __restrict__ FB,
                          const unsigned short* __restrict__ WtF,
                          const int* __restrict__ nbr,
                          float* __restrict__ out,
                          float* __restrict__ stats) {
    __shared__ unsigned short wlds[2][4096];   // 2 x 8 KB weight slice buffers
    __shared__ float lstats[128];
    const int tid = threadIdx.x;
    const int lane = tid & 63;
    const int wv = tid >> 6;
    const int m = lane & 15;
    const int q = lane >> 4;
    const int v0 = blockIdx.x * 128 + wv * 32;
    const bool tv[2] = { v0 < NVOX, v0 + 16 < NVOX };
    const int r[2] = { v0 + m, v0 + 16 + m };

    f32x4 acc[2][4];
#pragma unroll
    for (int t = 0; t < 2; ++t)
#pragma unroll
        for (int nt = 0; nt < 4; ++nt)
            acc[t][nt] = (f32x4){0.f, 0.f, 0.f, 0.f};
    if (tid < 128) lstats[tid] = 0.f;

    const bf16x8* fbv = (const bf16x8*)FB;      // 8 x bf16x8 per 128B row

    // ---- prologue: stage slice 0, gather slice 0, idx slice 1 ----
    {
        const unsigned short* g = WtF + wv * 1024 + lane * 8;   // slice 0, this wave's 2KB
        __builtin_amdgcn_global_load_lds((gconst_t*)g,         (lvoid_t*)&wlds[0][wv * 1024],       16, 0, 0);
        __builtin_amdgcn_global_load_lds((gconst_t*)(g + 512), (lvoid_t*)&wlds[0][wv * 1024 + 512], 16, 0, 0);
    }
    __builtin_amdgcn_sched_barrier(0);

    bf16x8 a[2][2];
    unsigned long long msk[2];
    int idxn[2];
#pragma unroll
    for (int t = 0; t < 2; ++t) {
        const int rr = tv[t] ? r[t] : m;        // clamped addr: load always issues
        const int i0 = nbr[rr];
        const int i = tv[t] ? i0 : -1;
        msk[t] = __ballot(i >= 0);
        const bf16x8* row = fbv + (size_t)(i < 0 ? NVOX : i) * 8;
        a[t][0] = row[q];
        a[t][1] = row[q + 4];
        const int i1 = nbr[NVOX + rr];
        idxn[t] = tv[t] ? i1 : -1;
    }
    // drain stage (oldest 2) + lstats ds_writes; keep gathers(4)+idx(2) in flight
    asm volatile("s_waitcnt vmcnt(6) lgkmcnt(0)" ::: "memory");
    __builtin_amdgcn_s_barrier();
    __builtin_amdgcn_sched_barrier(0);

    for (int k = 0; k < KVOL; ++k) {
        const int nb = k & 1;
        // 1. stage slice k+1 into wlds[nb^1] (pinned oldest in VMEM issue order)
        if (k + 1 < KVOL) {
            const unsigned short* g = WtF + (size_t)(k + 1) * 4096 + wv * 1024 + lane * 8;
            __builtin_amdgcn_global_load_lds((gconst_t*)g,         (lvoid_t*)&wlds[nb ^ 1][wv * 1024],       16, 0, 0);
            __builtin_amdgcn_global_load_lds((gconst_t*)(g + 512), (lvoid_t*)&wlds[nb ^ 1][wv * 1024 + 512], 16, 0, 0);
        }
        __builtin_amdgcn_sched_barrier(0);

        // 2. branchless gathers for slice k+1 (consumed next iteration)
        unsigned long long mn[2];
        bf16x8 an[2][2];
#pragma unroll
        for (int t = 0; t < 2; ++t) {
            mn[t] = __ballot(idxn[t] >= 0);
            const bf16x8* row = fbv + (size_t)(idxn[t] < 0 ? NVOX : idxn[t]) * 8;
            an[t][0] = row[q];
            an[t][1] = row[q + 4];
        }
        // 3. idx prefetch for slice k+2 (always 2 loads: count-uniform)
        const int kk = (k + 2 < KVOL) ? (k + 2) : 0;
        const int* nbp = nbr + (size_t)kk * NVOX;
        int idxf[2];
#pragma unroll
        for (int t = 0; t < 2; ++t) {
            const int rr = tv[t] ? r[t] : m;
            const int v = nbp[rr];
            idxf[t] = (tv[t] && (k + 2 < KVOL)) ? v : -1;
        }

        // 4. weight fragments for slice k from LDS (conflict-free b128)
        const unsigned short* wk = &wlds[nb][lane * 8];
        bf16x8 bfr[8];
#pragma unroll
        for (int h = 0; h < 8; ++h)
            bfr[h] = *(const bf16x8*)(wk + h * 512);

        // 5. compute slice k (a[] gathered one iteration ago)
#pragma unroll
        for (int t = 0; t < 2; ++t) {
            if (msk[t]) {
#pragma unroll
                for (int nt = 0; nt < 4; ++nt) {
                    acc[t][nt] = __builtin_amdgcn_mfma_f32_16x16x32_bf16(a[t][0], bfr[nt * 2 + 0], acc[t][nt], 0, 0, 0);
                    acc[t][nt] = __builtin_amdgcn_mfma_f32_16x16x32_bf16(a[t][1], bfr[nt * 2 + 1], acc[t][nt], 0, 0, 0);
                }
            }
        }

        // 6. shift pipeline
#pragma unroll
        for (int t = 0; t < 2; ++t) {
            a[t][0] = an[t][0];
            a[t][1] = an[t][1];
            msk[t] = mn[t];
            idxn[t] = idxf[t];
        }

        // 7. stage(k+1) complete, gathers+idx stay in flight; swap buffers
        asm volatile("s_waitcnt vmcnt(6)" ::: "memory");
        __builtin_amdgcn_s_barrier();
        __builtin_amdgcn_sched_barrier(0);
    }

    // ---- epilogue: stores + block-reduced BN statistics ----
    // D layout: col = m (channel nt*16+m), row = q*4 + rr (voxel within tile)
#pragma unroll
    for (int t = 0; t < 2; ++t) {
        if (tv[t]) {
            float* ob = out + (size_t)(v0 + t * 16 + q * 4) * CH + m;
#pragma unroll
            for (int nt = 0; nt < 4; ++nt)
#pragma unroll
                for (int rr = 0; rr < 4; ++rr)
                    ob[(size_t)rr * CH + nt * 16] = acc[t][nt][rr];
        }
    }

#pragma unroll
    for (int nt = 0; nt < 4; ++nt) {
        float s = 0.f, s2 = 0.f;
#pragma unroll
        for (int t = 0; t < 2; ++t)
#pragma unroll
            for (int rr = 0; rr < 4; ++rr) {
                const float x = acc[t][nt][rr];   // padded tiles stay exactly 0
                s += x;
                s2 = fmaf(x, x, s2);
            }
        s  += __shfl_xor(s, 16);  s  += __shfl_xor(s, 32);
        s2 += __shfl_xor(s2, 16); s2 += __shfl_xor(s2, 32);
        if (lane < 16) {
            atomicAdd(&lstats[nt * 16 + m], s);
            atomicAdd(&lstats[64 + nt * 16 + m], s2);
        }
    }
    __syncthreads();
    if (tid < 128) atomicAdd(&stats[tid], lstats[tid]);
}

// ---- bn_relu: grid-stride with inline finalize -----------------------------
__launch_bounds__(256)
__global__ void bn_relu(float* __restrict__ out, const float* __restrict__ stats,
                        const float* __restrict__ gamma, const float* __restrict__ beta) {
    __shared__ float sb[128];
    const int tid = threadIdx.x;
    if (tid < 64) {
        const float inv_n = 1.0f / (float)NVOX;
        const float mean = stats[tid] * inv_n;
        const float var = stats[64 + tid] * inv_n - mean * mean;
        const float sc = gamma[tid] * rsqrtf(var + EPSV);
        sb[tid] = sc;
        sb[64 + tid] = beta[tid] - mean * sc;
    }
    __syncthreads();
    float4* o4 = (float4*)out;
    for (int e = blockIdx.x * 256 + tid; e < NF4; e += 960 * 256) {
        float4 x = o4[e];
        const int cb = (e & 15) * 4;
        x.x = fmaxf(fmaf(x.x, sb[cb + 0], sb[64 + cb + 0]), 0.f);
        x.y = fmaxf(fmaf(x.y, sb[cb + 1], sb[64 + cb + 1]), 0.f);
        x.z = fmaxf(fmaf(x.z, sb[cb + 2], sb[64 + cb + 2]), 0.f);
        x.w = fmaxf(fmaf(x.w, sb[cb + 3], sb[64 + cb + 3]), 0.f);
        o4[e] = x;
    }
}

extern "C" void kernel_launch(void* const* d_in, const int* in_sizes, int n_in,
                              void* d_out, int out_size, void* d_ws, size_t ws_size,
                              hipStream_t stream) {
    const float* feats  = (const float*)d_in[0];   // [N, 64]
    const float* weight = (const float*)d_in[1];   // [27, 64, 64]
    const float* gamma  = (const float*)d_in[2];   // [64]
    const float* beta   = (const float*)d_in[3];   // [64]
    const int*   nbr    = (const int*)d_in[4];     // [27, N]
    float* out = (float*)d_out;                    // [N, 64]

    // ws layout: [0,512) stats; [512, 512+221184) WtF bf16 frag-order;
    //            [221696, 221696+15360128) featsB bf16 [N+1][64] (sentinel row N)
    float* stats = (float*)d_ws;
    unsigned short* WtF = (unsigned short*)((char*)d_ws + 512);
    unsigned short* FB  = (unsigned short*)((char*)d_ws + 512 + 221184);

    prep<<<WBLK + FBLK, 256, 0, stream>>>(weight, feats, WtF, FB, stats);
    conv_mfma<<<(NVOX + 127) / 128, 256, 0, stream>>>(FB, WtF, nbr, out, stats);
    bn_relu<<<960, 256, 0, stream>>>(out, stats, gamma, beta);
}

// Round 4
// 150.341 us; speedup vs baseline: 1.0846x; 1.0215x over previous
//
#include <hip/hip_runtime.h>

#define NVOX 120000
#define KVOL 27
#define CH 64
#define TOTAL (NVOX * CH)
#define NF4 (TOTAL / 4)
#define EPSV 1e-5f

typedef __attribute__((ext_vector_type(8))) short bf16x8;
typedef __attribute__((ext_vector_type(8))) unsigned short u16x8;
typedef __attribute__((ext_vector_type(4))) float f32x4;
typedef __attribute__((address_space(1))) const void gconst_t;
typedef __attribute__((address_space(3))) void lvoid_t;

__device__ __forceinline__ unsigned short f2bf(float f) {
    unsigned int u = __builtin_bit_cast(unsigned int, f);
    u += 0x7FFFu + ((u >> 16) & 1u);          // RNE
    return (unsigned short)(u >> 16);
}

// ---- prep: weight shuffle + feats->bf16 + sentinel row + stats zero --------
// weight fp32 [k][c][d] -> bf16 MFMA-fragment order:
//   wtf[((k*8 + grp)*64 + lane)*8 + j], grp=(d>>4)*2+(c>>5),
//   lane=((c&31)>>3)*16+(d&15), j=c&7   (validated rounds 4-8, unchanged)
// feats fp32 [N][64] -> bf16 [N+1][64], row N = zeros (sentinel for idx<0)
#define WBLK 432                 // 27*64*64 / 256
#define FBLK 3750                // 7,680,000 / (256*8)
__global__ void prep(const float* __restrict__ w, const float* __restrict__ feats,
                     unsigned short* __restrict__ wtf, unsigned short* __restrict__ fb,
                     float* __restrict__ stats) {
    const int b = blockIdx.x;
    const int tid = threadIdx.x;
    if (b < WBLK) {
        const int t = b * 256 + tid;           // t = k*4096 + c*64 + d (coalesced read)
        const int d = t & 63, c = (t >> 6) & 63, k = t >> 12;
        const int grp = (d >> 4) * 2 + (c >> 5);
        const int l = ((c & 31) >> 3) * 16 + (d & 15);
        const int j = c & 7;
        wtf[(((size_t)k * 8 + grp) * 64 + l) * 8 + j] = f2bf(w[t]);
        if (b == 0 && tid < 128) stats[tid] = 0.f;
        if (b == 1 && tid < 8) ((u16x8*)fb)[(size_t)NVOX * 8 + tid] = (u16x8)0;
    } else {
        const int t = (b - WBLK) * 256 + tid;  // handles 8 consecutive floats
        const float4* src = (const float4*)feats + (size_t)t * 2;
        const float4 p0 = src[0];
        const float4 p1 = src[1];
        u16x8 v = {f2bf(p0.x), f2bf(p0.y), f2bf(p0.z), f2bf(p0.w),
                   f2bf(p1.x), f2bf(p1.y), f2bf(p1.z), f2bf(p1.w)};
        ((u16x8*)fb)[t] = v;
    }
}

// ---- conv: 2-slice barrier phases (14 vs 27), ping-pong gather regs --------
// Per phase p: stage 2 weight slices for p+1 (global_load_lds, 16 KB),
// gather phase p+1 A-fragments (branchless sentinel), prefetch phase p+2
// indices, compute phase p (2 slices x 2 tiles x 8 MFMA, per-tile skip,
// setprio(1) around the MFMA cluster). Counted s_waitcnt vmcnt(N) per phase
// drains EXACTLY the stage loads and keeps gathers+idx in flight across the
// s_barrier. VMEM ledger (steady state): prev gathers/idx force-drained by
// their consumers before new issue -> at wait: stage(4)+gathers(8)+idx(4)=16
// outstanding, vmcnt(12) drains the stage only. Tail phases exact (10/4).
// Masks are wave-uniform bools (SGPR) to keep VGPRs < 128 (no-spill is a
// correctness requirement: scratch ops would corrupt the counted waits).
// 938 blocks * 128 vox; LDS 33.3 KB -> 4 blk/CU.
#define PHASE(P, BUF, AC, MC, AN, MN_, NSSL, NGSL, NISL, WAITN)                 \
  {                                                                             \
    /* 1. stage phase P+1 slices (2*(P)+2, +3) into wlds[BUF^1] */              \
    {                                                                           \
      const unsigned short* gq = WtF + (size_t)(2*(P)+2) * 4096 + wv*1024 + lane*8; \
      __builtin_amdgcn_global_load_lds((gconst_t*)gq,         (lvoid_t*)&wlds[(BUF)^1][wv*1024],       16, 0, 0); \
      __builtin_amdgcn_global_load_lds((gconst_t*)(gq + 512), (lvoid_t*)&wlds[(BUF)^1][wv*1024 + 512], 16, 0, 0); \
      if ((NSSL) > 1) {                                                         \
        __builtin_amdgcn_global_load_lds((gconst_t*)(gq + 4096), (lvoid_t*)&wlds[(BUF)^1][4096 + wv*1024],       16, 0, 0); \
        __builtin_amdgcn_global_load_lds((gconst_t*)(gq + 4608), (lvoid_t*)&wlds[(BUF)^1][4096 + wv*1024 + 512], 16, 0, 0); \
      }                                                                         \
    }                                                                           \
    __builtin_amdgcn_sched_barrier(0);                                          \
    /* 2. branchless gathers for phase P+1 (consumed next phase) */             \
    _Pragma("unroll")                                                           \
    for (int sl = 0; sl < (NGSL); ++sl)                                         \
      _Pragma("unroll")                                                         \
      for (int t = 0; t < 2; ++t) {                                             \
        const int ii = idxn[sl][t];                                             \
        MN_[sl][t] = (__ballot(ii >= 0) != 0ULL);                               \
        const bf16x8* rw = fbv + (size_t)(ii < 0 ? NVOX : ii) * 8;              \
        AN[sl][t][0] = rw[q];                                                   \
        AN[sl][t][1] = rw[q + 4];                                               \
      }                                                                         \
    /* 3. idx prefetch for phase P+2 */                                         \
    _Pragma("unroll")                                                           \
    for (int sl = 0; sl < (NISL); ++sl)                                         \
      _Pragma("unroll")                                                         \
      for (int t = 0; t < 2; ++t) {                                             \
        const int rr = tv[t] ? r[t] : m;                                        \
        const int vv = nbr[(size_t)(2*(P)+4+sl) * NVOX + rr];                   \
        idxn[sl][t] = tv[t] ? vv : -1;                                          \
      }                                                                         \
    /* 4. compute phase P (slices 2P, 2P+1) from wlds[BUF] */                   \
    __builtin_amdgcn_s_setprio(1);                                              \
    _Pragma("unroll")                                                           \
    for (int sl = 0; sl < 2; ++sl) {                                            \
      if (MC[sl][0] | MC[sl][1]) {                                              \
        const unsigned short* wk = &wlds[BUF][sl*4096 + lane*8];                \
        _Pragma("unroll")                                                       \
        for (int nt = 0; nt < 4; ++nt) {                                        \
          const bf16x8 b0 = *(const bf16x8*)(wk + (nt*2    )*512);              \
          const bf16x8 b1 = *(const bf16x8*)(wk + (nt*2 + 1)*512);              \
          _Pragma("unroll")                                                     \
          for (int t = 0; t < 2; ++t)                                           \
            if (MC[sl][t]) {                                                    \
              acc[t][nt] = __builtin_amdgcn_mfma_f32_16x16x32_bf16(AC[sl][t][0], b0, acc[t][nt], 0, 0, 0); \
              acc[t][nt] = __builtin_amdgcn_mfma_f32_16x16x32_bf16(AC[sl][t][1], b1, acc[t][nt], 0, 0, 0); \
            }                                                                   \
        }                                                                       \
      }                                                                         \
    }                                                                           \
    __builtin_amdgcn_s_setprio(0);                                              \
    /* 5. drain exactly the stage; gathers+idx stay in flight */                \
    asm volatile("s_waitcnt vmcnt(" #WAITN ")" ::: "memory");                   \
    __builtin_amdgcn_s_barrier();                                               \
    __builtin_amdgcn_sched_barrier(0);                                          \
  }

__launch_bounds__(256, 4)
__global__ void conv_mfma(const unsigned short* __restrict__ FB,
                          const unsigned short* __restrict__ WtF,
                          const int* __restrict__ nbr,
                          float* __restrict__ out,
                          float* __restrict__ stats) {
    __shared__ unsigned short wlds[2][8192];   // 2 x (2 slices x 8 KB)
    __shared__ float lstats[128];
    const int tid = threadIdx.x;
    const int lane = tid & 63;
    const int wv = tid >> 6;
    const int m = lane & 15;
    const int q = lane >> 4;
    const int v0 = blockIdx.x * 128 + wv * 32;
    const bool tv[2] = { v0 < NVOX, v0 + 16 < NVOX };
    const int r[2] = { v0 + m, v0 + 16 + m };

    f32x4 acc[2][4];
#pragma unroll
    for (int t = 0; t < 2; ++t)
#pragma unroll
        for (int nt = 0; nt < 4; ++nt)
            acc[t][nt] = (f32x4){0.f, 0.f, 0.f, 0.f};
    if (tid < 128) lstats[tid] = 0.f;

    const bf16x8* fbv = (const bf16x8*)FB;      // 8 x bf16x8 per 128B row

    bf16x8 aA[2][2][2], aB[2][2][2];            // [slice][tile][frag]
    bool mA[2][2], mB[2][2];                    // wave-uniform tile-valid flags
    int idxn[2][2];

    // ---- prologue: stage phase 0 (slices 0,1), gather phase 0, idx phase 1 ----
    {
        const unsigned short* g0 = WtF + wv * 1024 + lane * 8;
        __builtin_amdgcn_global_load_lds((gconst_t*)g0,          (lvoid_t*)&wlds[0][wv*1024],              16, 0, 0);
        __builtin_amdgcn_global_load_lds((gconst_t*)(g0 + 512),  (lvoid_t*)&wlds[0][wv*1024 + 512],        16, 0, 0);
        __builtin_amdgcn_global_load_lds((gconst_t*)(g0 + 4096), (lvoid_t*)&wlds[0][4096 + wv*1024],       16, 0, 0);
        __builtin_amdgcn_global_load_lds((gconst_t*)(g0 + 4608), (lvoid_t*)&wlds[0][4096 + wv*1024 + 512], 16, 0, 0);
    }
    __builtin_amdgcn_sched_barrier(0);
#pragma unroll
    for (int sl = 0; sl < 2; ++sl)
#pragma unroll
        for (int t = 0; t < 2; ++t) {
            const int rr = tv[t] ? r[t] : m;      // clamped addr: load always issues
            const int v = nbr[(size_t)sl * NVOX + rr];
            const int ii = tv[t] ? v : -1;
            mA[sl][t] = (__ballot(ii >= 0) != 0ULL);
            const bf16x8* rw = fbv + (size_t)(ii < 0 ? NVOX : ii) * 8;
            aA[sl][t][0] = rw[q];
            aA[sl][t][1] = rw[q + 4];
        }
#pragma unroll
    for (int sl = 0; sl < 2; ++sl)
#pragma unroll
        for (int t = 0; t < 2; ++t) {
            const int rr = tv[t] ? r[t] : m;
            const int v = nbr[(size_t)(2 + sl) * NVOX + rr];
            idxn[sl][t] = tv[t] ? v : -1;
        }
    // stage(4) drained, gathers(8)+idx(4) in flight; lstats ds_writes drained
    asm volatile("s_waitcnt vmcnt(12) lgkmcnt(0)" ::: "memory");
    __builtin_amdgcn_s_barrier();
    __builtin_amdgcn_sched_barrier(0);

    // ---- 13 staged phases + final compute-only phase ----
    PHASE(0,  0, aA, mA, aB, mB, 2, 2, 2, 12)
    PHASE(1,  1, aB, mB, aA, mA, 2, 2, 2, 12)
    PHASE(2,  0, aA, mA, aB, mB, 2, 2, 2, 12)
    PHASE(3,  1, aB, mB, aA, mA, 2, 2, 2, 12)
    PHASE(4,  0, aA, mA, aB, mB, 2, 2, 2, 12)
    PHASE(5,  1, aB, mB, aA, mA, 2, 2, 2, 12)
    PHASE(6,  0, aA, mA, aB, mB, 2, 2, 2, 12)
    PHASE(7,  1, aB, mB, aA, mA, 2, 2, 2, 12)
    PHASE(8,  0, aA, mA, aB, mB, 2, 2, 2, 12)
    PHASE(9,  1, aB, mB, aA, mA, 2, 2, 2, 12)
    PHASE(10, 0, aA, mA, aB, mB, 2, 2, 2, 12)
    PHASE(11, 1, aB, mB, aA, mA, 2, 2, 1, 10)   // idx only for phase 13 slice 26
    PHASE(12, 0, aA, mA, aB, mB, 1, 1, 0, 4)    // stage+gather slice 26 only

    // phase 13 = slice 26 only: staged in wlds[1], gathered in aB[0]/mB[0]
    __builtin_amdgcn_s_setprio(1);
    if (mB[0][0] | mB[0][1]) {
        const unsigned short* wk = &wlds[1][lane * 8];
#pragma unroll
        for (int nt = 0; nt < 4; ++nt) {
            const bf16x8 b0 = *(const bf16x8*)(wk + (nt*2    )*512);
            const bf16x8 b1 = *(const bf16x8*)(wk + (nt*2 + 1)*512);
#pragma unroll
            for (int t = 0; t < 2; ++t)
                if (mB[0][t]) {
                    acc[t][nt] = __builtin_amdgcn_mfma_f32_16x16x32_bf16(aB[0][t][0], b0, acc[t][nt], 0, 0, 0);
                    acc[t][nt] = __builtin_amdgcn_mfma_f32_16x16x32_bf16(aB[0][t][1], b1, acc[t][nt], 0, 0, 0);
                }
        }
    }
    __builtin_amdgcn_s_setprio(0);

    // ---- epilogue: stores + block-reduced BN statistics ----
    // D layout: col = m (channel nt*16+m), row = q*4 + rr (voxel within tile)
#pragma unroll
    for (int t = 0; t < 2; ++t) {
        if (tv[t]) {
            float* ob = out + (size_t)(v0 + t * 16 + q * 4) * CH + m;
#pragma unroll
            for (int nt = 0; nt < 4; ++nt)
#pragma unroll
                for (int rr = 0; rr < 4; ++rr)
                    ob[(size_t)rr * CH + nt * 16] = acc[t][nt][rr];
        }
    }

#pragma unroll
    for (int nt = 0; nt < 4; ++nt) {
        float s = 0.f, s2 = 0.f;
#pragma unroll
        for (int t = 0; t < 2; ++t)
#pragma unroll
            for (int rr = 0; rr < 4; ++rr) {
                const float x = acc[t][nt][rr];   // padded tiles stay exactly 0
                s += x;
                s2 = fmaf(x, x, s2);
            }
        s  += __shfl_xor(s, 16);  s  += __shfl_xor(s, 32);
        s2 += __shfl_xor(s2, 16); s2 += __shfl_xor(s2, 32);
        if (lane < 16) {
            atomicAdd(&lstats[nt * 16 + m], s);
            atomicAdd(&lstats[64 + nt * 16 + m], s2);
        }
    }
    __syncthreads();
    if (tid < 128) atomicAdd(&stats[tid], lstats[tid]);
}

// ---- bn_relu: grid-stride with inline finalize -----------------------------
__launch_bounds__(256)
__global__ void bn_relu(float* __restrict__ out, const float* __restrict__ stats,
                        const float* __restrict__ gamma, const float* __restrict__ beta) {
    __shared__ float sb[128];
    const int tid = threadIdx.x;
    if (tid < 64) {
        const float inv_n = 1.0f / (float)NVOX;
        const float mean = stats[tid] * inv_n;
        const float var = stats[64 + tid] * inv_n - mean * mean;
        const float sc = gamma[tid] * rsqrtf(var + EPSV);
        sb[tid] = sc;
        sb[64 + tid] = beta[tid] - mean * sc;
    }
    __syncthreads();
    float4* o4 = (float4*)out;
    for (int e = blockIdx.x * 256 + tid; e < NF4; e += 960 * 256) {
        float4 x = o4[e];
        const int cb = (e & 15) * 4;
        x.x = fmaxf(fmaf(x.x, sb[cb + 0], sb[64 + cb + 0]), 0.f);
        x.y = fmaxf(fmaf(x.y, sb[cb + 1], sb[64 + cb + 1]), 0.f);
        x.z = fmaxf(fmaf(x.z, sb[cb + 2], sb[64 + cb + 2]), 0.f);
        x.w = fmaxf(fmaf(x.w, sb[cb + 3], sb[64 + cb + 3]), 0.f);
        o4[e] = x;
    }
}

extern "C" void kernel_launch(void* const* d_in, const int* in_sizes, int n_in,
                              void* d_out, int out_size, void* d_ws, size_t ws_size,
                              hipStream_t stream) {
    const float* feats  = (const float*)d_in[0];   // [N, 64]
    const float* weight = (const float*)d_in[1];   // [27, 64, 64]
    const float* gamma  = (const float*)d_in[2];   // [64]
    const float* beta   = (const float*)d_in[3];   // [64]
    const int*   nbr    = (const int*)d_in[4];     // [27, N]
    float* out = (float*)d_out;                    // [N, 64]

    // ws layout: [0,512) stats; [512, 512+221184) WtF bf16 frag-order;
    //            [221696, 221696+15360128) featsB bf16 [N+1][64] (sentinel row N)
    float* stats = (float*)d_ws;
    unsigned short* WtF = (unsigned short*)((char*)d_ws + 512);
    unsigned short* FB  = (unsigned short*)((char*)d_ws + 512 + 221184);

    prep<<<WBLK + FBLK, 256, 0, stream>>>(weight, feats, WtF, FB, stats);
    conv_mfma<<<(NVOX + 127) / 128, 256, 0, stream>>>(FB, WtF, nbr, out, stats);
    bn_relu<<<960, 256, 0, stream>>>(out, stats, gamma, beta);
}